// Round 5
// baseline (569.558 us; speedup 1.0000x reference)
//
#include <hip/hip_runtime.h>
#include <stdint.h>

// B = 1048576 rows, HID = 64. Residual MLP with training-mode BatchNorm.
// Recompute-fused layer kernels + bf16 activations (128 MB in d_ws).
// Round 5: wave-autonomous big kernels — 64-thread blocks (1 wave), ZERO
// barriers, per-wave stats rows (no LDS atomics), direct-global MFMA A-frag
// loads (LDS only for the C-layout y_old access), 2x32-row subtiles per wave
// with pipelined frag prefetch.
// MFMA 16x16x32 bf16 layouts (verified gfx950 mappings):
//   A: row = lane&15, k = (lane>>4)*8 + j   (16B contiguous -> b128)
//   B: col = lane&15, k = (lane>>4)*8 + j   (load from W^T, row-major)
//   C/D: col = lane&15, row = (lane>>4)*4 + reg

#define NROWS 1048576
#define EPS 1e-5f
#define INV_B 9.5367431640625e-07f  // 1/2^20 exact
#define LOG2E2 2.885390081777927f   // 2*log2(e)
#define BIGGRID 16384               // blocks of 64 threads; 64 rows each

typedef __attribute__((ext_vector_type(8))) short bfrag;   // 8 bf16 = 4 VGPR
typedef __attribute__((ext_vector_type(4))) float facc;    // MFMA C/D
typedef __attribute__((ext_vector_type(4))) float f4v;

__device__ __forceinline__ float bf2f(short s) {
  union { unsigned u; float f; } v;
  v.u = ((unsigned)(unsigned short)s) << 16;
  return v.f;
}
__device__ __forceinline__ short f2bf(float f) {
  union { float f; unsigned u; } v;
  v.f = f;
  unsigned r = v.u + 0x7FFFu + ((v.u >> 16) & 1u);  // RNE
  return (short)(r >> 16);
}
// tanh = 1 - 2/(e^{2x}+1); v_exp + v_rcp, saturates correctly at +-inf
__device__ __forceinline__ float tanh_fast(float x) {
  float e = __builtin_amdgcn_exp2f(x * LOG2E2);
  return 1.f - 2.f * __builtin_amdgcn_rcpf(e + 1.f);
}

// ---------------- reduce: P[nb][W] -> atomicAdd into S[W] ----------------
template <int W>
__global__ __launch_bounds__(256) void k_reduce(const float* __restrict__ P,
                                                float* __restrict__ S,
                                                int rows_per_blk) {
  __shared__ float red[256];
  const int tid = threadIdx.x;
  const int col = tid % W;
  const int grp = tid / W;
  const int G = 256 / W;
  size_t r0 = (size_t)blockIdx.x * rows_per_blk;
  float s = 0.f;
  for (int r = grp; r < rows_per_blk; r += G) s += P[(r0 + r) * W + col];
  red[tid] = s;
  __syncthreads();
  if (tid < W) {
    float t = 0.f;
#pragma unroll 4
    for (int g = 0; g < G; ++g) t += red[g * W + tid];
    atomicAdd(&S[tid], t);
  }
}

// ---------------- small kernels ----------------

__global__ __launch_bounds__(256) void k_stats_x(const float* __restrict__ x,
                                                 float* __restrict__ P) {
  __shared__ float red[4][8];
  const int tid = threadIdx.x;
  const int wave = tid >> 6;
  size_t base = (size_t)blockIdx.x * 1024 + tid;
  float s[4] = {0.f, 0.f, 0.f, 0.f}, q[4] = {0.f, 0.f, 0.f, 0.f};
#pragma unroll
  for (int it = 0; it < 4; ++it) {
    f4v v = *(const f4v*)(x + (base + (size_t)it * 256) * 4);
#pragma unroll
    for (int k = 0; k < 4; ++k) { s[k] += v[k]; q[k] = fmaf(v[k], v[k], q[k]); }
  }
#pragma unroll
  for (int off = 32; off > 0; off >>= 1) {
#pragma unroll
    for (int k = 0; k < 4; ++k) {
      s[k] += __shfl_xor(s[k], off);
      q[k] += __shfl_xor(q[k], off);
    }
  }
  if ((tid & 63) == 0) {
#pragma unroll
    for (int k = 0; k < 4; ++k) { red[wave][k] = s[k]; red[wave][4 + k] = q[k]; }
  }
  __syncthreads();
  if (tid < 8)
    P[blockIdx.x * 8 + tid] =
        red[0][tid] + red[1][tid] + red[2][tid] + red[3][tid];
}

__global__ __launch_bounds__(256) void k_stats_z1(
    const float* __restrict__ x, const float* __restrict__ bn0g,
    const float* __restrict__ bn0b, const float* __restrict__ W0,
    const float* __restrict__ b0, const float* __restrict__ sx,
    float* __restrict__ P) {
  __shared__ float red[2][4][64];
  const int tid = threadIdx.x;
  const int lane = tid & 63;
  const int wave = tid >> 6;
  int gw = blockIdx.x * 4 + wave;
  float sc[4], sh[4];
#pragma unroll
  for (int k = 0; k < 4; ++k) {
    float mean = sx[k] * INV_B;
    float var = fmaf(-mean, mean, sx[4 + k] * INV_B);
    float rs = rsqrtf(var + EPS);
    sc[k] = bn0g[k] * rs;
    sh[k] = fmaf(-sc[k], mean, bn0b[k]);
  }
  float w[4];
#pragma unroll
  for (int k = 0; k < 4; ++k) w[k] = W0[k * 64 + lane];
  float bj = b0[lane];
  float s = 0.f, q = 0.f;
  size_t r0 = (size_t)gw * 256;
  for (int r = 0; r < 256; ++r) {
    f4v xv = *(const f4v*)(x + (r0 + r) * 4);
    float acc = bj;
#pragma unroll
    for (int k = 0; k < 4; ++k)
      acc = fmaf(fmaf(xv[k], sc[k], sh[k]), w[k], acc);
    float z = tanh_fast(acc);
    s += z;
    q = fmaf(z, z, q);
  }
  red[0][wave][lane] = s;
  red[1][wave][lane] = q;
  __syncthreads();
  if (tid < 128) {
    int which = tid >> 6, c = tid & 63;
    P[blockIdx.x * 128 + tid] = red[which][0][c] + red[which][1][c] +
                                red[which][2][c] + red[which][3][c];
  }
}

__global__ __launch_bounds__(256) void k_prep(const float* __restrict__ Wh,
                                              short* __restrict__ WT) {
  int idx = blockIdx.x * 256 + threadIdx.x;  // 16384 total
  int l = idx >> 12, rem = idx & 4095, k = rem >> 6, c = rem & 63;
  WT[l * 4096 + c * 64 + k] = f2bf(Wh[l * 4096 + k * 64 + c]);
}

// ---------------- big fused kernels: 1 wave / 64 rows (2x32 subtiles) ------

// K_first: Y1 = BN(tanh(bn0(x)@W0+b0)), write Y1 bf16,
// per-wave partial stats of Z2 = tanh(Y1 @ W_hid0 + b_hid0) -> P[bid][128]
__global__ __launch_bounds__(64) void k_first(
    const float* __restrict__ x, const float* __restrict__ bn0g,
    const float* __restrict__ bn0b, const float* __restrict__ W0,
    const float* __restrict__ b0, const float* __restrict__ gamma0,
    const float* __restrict__ beta0, const float* __restrict__ sx,
    const float* __restrict__ s1, const short* __restrict__ WTb,
    const float* __restrict__ bb, float* __restrict__ P,
    short* __restrict__ Y) {
  __shared__ __align__(16) float lds_x[32 * 4];
  __shared__ __align__(16) short ly[32 * 72];

  const int lane = threadIdx.x & 63;
  const int l15 = lane & 15;
  const int q = lane >> 4;
  const size_t r0 = (size_t)blockIdx.x * 64;

  // x prefetch for subtile 0
  f4v xp;
  if (lane < 32) xp = *(const f4v*)(x + (r0 + lane) * 4);

  float sc0[4], sh0[4];
#pragma unroll
  for (int k = 0; k < 4; ++k) {
    float mean = sx[k] * INV_B;
    float var = fmaf(-mean, mean, sx[4 + k] * INV_B);
    float rs = rsqrtf(var + EPS);
    sc0[k] = bn0g[k] * rs;
    sh0[k] = fmaf(-sc0[k], mean, bn0b[k]);
  }
  float w0c[4];
#pragma unroll
  for (int k = 0; k < 4; ++k) w0c[k] = W0[k * 64 + lane];
  float b0c = b0[lane];
  float mean1 = s1[lane] * INV_B;
  float var1 = fmaf(-mean1, mean1, s1[64 + lane] * INV_B);
  float A1c = gamma0[lane] * rsqrtf(var1 + EPS);
  float B1c = fmaf(-A1c, mean1, beta0[lane]);
  float bbv[4];
  bfrag bwb[4][2];
#pragma unroll
  for (int nt = 0; nt < 4; ++nt) {
    bbv[nt] = bb[nt * 16 + l15];
#pragma unroll
    for (int kt = 0; kt < 2; ++kt)
      bwb[nt][kt] =
          *(const bfrag*)(WTb + (nt * 16 + l15) * 64 + kt * 32 + q * 8);
  }

  float sAcc[4] = {0.f, 0.f, 0.f, 0.f}, qAcc[4] = {0.f, 0.f, 0.f, 0.f};

#pragma unroll
  for (int t = 0; t < 2; ++t) {
    const size_t rt = r0 + t * 32;
    if (lane < 32) *(f4v*)&lds_x[lane * 4] = xp;
    if (t == 0 && lane < 32) xp = *(const f4v*)(x + (r0 + 32 + lane) * 4);

    // phase A: Y1 rows (local 0..31, col = lane)
    for (int e = 0; e < 32; ++e) {
      float acc = b0c;
#pragma unroll
      for (int k = 0; k < 4; ++k)
        acc = fmaf(fmaf(lds_x[e * 4 + k], sc0[k], sh0[k]), w0c[k], acc);
      float z = tanh_fast(acc);
      ly[e * 72 + lane] = f2bf(fmaf(A1c, z, B1c));
    }

    // phase B: frags from LDS, store Y1, stats matmul
    bfrag af[2][2];
#pragma unroll
    for (int mt = 0; mt < 2; ++mt)
#pragma unroll
      for (int kt = 0; kt < 2; ++kt) {
        af[mt][kt] =
            *(const bfrag*)&ly[(mt * 16 + l15) * 72 + kt * 32 + q * 8];
        *(bfrag*)(Y + (rt + mt * 16 + l15) * 64 + kt * 32 + q * 8) =
            af[mt][kt];
      }
    facc acc2[2][4];
#pragma unroll
    for (int mt = 0; mt < 2; ++mt)
#pragma unroll
      for (int nt = 0; nt < 4; ++nt) {
        acc2[mt][nt][0] = bbv[nt]; acc2[mt][nt][1] = bbv[nt];
        acc2[mt][nt][2] = bbv[nt]; acc2[mt][nt][3] = bbv[nt];
      }
#pragma unroll
    for (int mt = 0; mt < 2; ++mt)
#pragma unroll
      for (int nt = 0; nt < 4; ++nt)
#pragma unroll
        for (int kt = 0; kt < 2; ++kt)
          acc2[mt][nt] = __builtin_amdgcn_mfma_f32_16x16x32_bf16(
              af[mt][kt], bwb[nt][kt], acc2[mt][nt], 0, 0, 0);
#pragma unroll
    for (int nt = 0; nt < 4; ++nt)
#pragma unroll
      for (int mt = 0; mt < 2; ++mt)
#pragma unroll
        for (int i = 0; i < 4; ++i) {
          float z = tanh_fast(acc2[mt][nt][i]);
          sAcc[nt] += z;
          qAcc[nt] = fmaf(z, z, qAcc[nt]);
        }
  }

#pragma unroll
  for (int nt = 0; nt < 4; ++nt) {
    float s = sAcc[nt], ss = qAcc[nt];
    s += __shfl_xor(s, 16); s += __shfl_xor(s, 32);
    ss += __shfl_xor(ss, 16); ss += __shfl_xor(ss, 32);
    if (q == 0) {
      P[(size_t)blockIdx.x * 128 + nt * 16 + l15] = s;
      P[(size_t)blockIdx.x * 128 + 64 + nt * 16 + l15] = ss;
    }
  }
}

// K_mid: recompute Z_a = tanh(Y@WTa+ba), Ynew = BN(Z_a)+Y, store Ynew;
// stats matmul with WTb -> P[bid][128]. Wave-autonomous, barrier-free.
__global__ __launch_bounds__(64) void k_mid(
    short* __restrict__ Y, const short* __restrict__ WTa,
    const float* __restrict__ ba, const float* __restrict__ ga,
    const float* __restrict__ bea, const float* __restrict__ sa,
    const short* __restrict__ WTb, const float* __restrict__ bb,
    float* __restrict__ P) {
  __shared__ __align__(16) short ly[32 * 72];

  const int lane = threadIdx.x & 63;
  const int l15 = lane & 15;
  const int q = lane >> 4;
  const size_t r0 = (size_t)blockIdx.x * 64;

  // subtile-0 A-frags direct from global (critical path: load -> MFMA)
  bfrag afn[2][2];
#pragma unroll
  for (int mt = 0; mt < 2; ++mt)
#pragma unroll
    for (int kt = 0; kt < 2; ++kt)
      afn[mt][kt] =
          *(const bfrag*)(Y + (r0 + mt * 16 + l15) * 64 + kt * 32 + q * 8);

  float Av[4], Bv[4], bav[4];
#pragma unroll
  for (int nt = 0; nt < 4; ++nt) {
    int c = nt * 16 + l15;
    float mean = sa[c] * INV_B;
    float var = fmaf(-mean, mean, sa[64 + c] * INV_B);
    float A = ga[c] * rsqrtf(var + EPS);
    Av[nt] = A;
    Bv[nt] = fmaf(-A, mean, bea[c]);
    bav[nt] = ba[c];
  }
  bfrag bwa[4][2];
#pragma unroll
  for (int nt = 0; nt < 4; ++nt)
#pragma unroll
    for (int kt = 0; kt < 2; ++kt)
      bwa[nt][kt] =
          *(const bfrag*)(WTa + (nt * 16 + l15) * 64 + kt * 32 + q * 8);

  float sAcc[4] = {0.f, 0.f, 0.f, 0.f}, qAcc[4] = {0.f, 0.f, 0.f, 0.f};

#pragma unroll
  for (int t = 0; t < 2; ++t) {
    const size_t rt = r0 + t * 32;
    bfrag af[2][2];
#pragma unroll
    for (int mt = 0; mt < 2; ++mt)
#pragma unroll
      for (int kt = 0; kt < 2; ++kt) {
        af[mt][kt] = afn[mt][kt];
        // stage to LDS for the scalar C-layout y_old access (off critical path)
        *(bfrag*)&ly[(mt * 16 + l15) * 72 + kt * 32 + q * 8] = af[mt][kt];
      }
    if (t == 0) {
#pragma unroll
      for (int mt = 0; mt < 2; ++mt)
#pragma unroll
        for (int kt = 0; kt < 2; ++kt)
          afn[mt][kt] = *(const bfrag*)(Y + (r0 + 32 + mt * 16 + l15) * 64 +
                                        kt * 32 + q * 8);
    }

    // matmul1: recompute Z_a (bit-identical to producer's stats matmul)
    facc acc[2][4];
#pragma unroll
    for (int mt = 0; mt < 2; ++mt)
#pragma unroll
      for (int nt = 0; nt < 4; ++nt) {
        acc[mt][nt][0] = bav[nt]; acc[mt][nt][1] = bav[nt];
        acc[mt][nt][2] = bav[nt]; acc[mt][nt][3] = bav[nt];
      }
#pragma unroll
    for (int mt = 0; mt < 2; ++mt)
#pragma unroll
      for (int nt = 0; nt < 4; ++nt)
#pragma unroll
        for (int kt = 0; kt < 2; ++kt)
          acc[mt][nt] = __builtin_amdgcn_mfma_f32_16x16x32_bf16(
              af[mt][kt], bwa[nt][kt], acc[mt][nt], 0, 0, 0);

    // BN + residual, in-place in ly (owner-lane elements only)
#pragma unroll
    for (int mt = 0; mt < 2; ++mt)
#pragma unroll
      for (int nt = 0; nt < 4; ++nt) {
        int c = nt * 16 + l15;
        float A = Av[nt], Bc = Bv[nt];
#pragma unroll
        for (int i = 0; i < 4; ++i) {
          int rl = mt * 16 + q * 4 + i;
          float z = tanh_fast(acc[mt][nt][i]);
          float yo = bf2f(ly[rl * 72 + c]);
          ly[rl * 72 + c] = f2bf(fmaf(A, z, Bc) + yo);
        }
      }

    // phase 4: frags of Ynew from LDS, store; stats matmul (late B-frags)
    bfrag af2[2][2];
#pragma unroll
    for (int mt = 0; mt < 2; ++mt)
#pragma unroll
      for (int kt = 0; kt < 2; ++kt) {
        af2[mt][kt] =
            *(const bfrag*)&ly[(mt * 16 + l15) * 72 + kt * 32 + q * 8];
        *(bfrag*)(Y + (rt + mt * 16 + l15) * 64 + kt * 32 + q * 8) =
            af2[mt][kt];
      }
    float bbv[4];
    bfrag bwb[4][2];
#pragma unroll
    for (int nt = 0; nt < 4; ++nt) {
      bbv[nt] = bb[nt * 16 + l15];
#pragma unroll
      for (int kt = 0; kt < 2; ++kt)
        bwb[nt][kt] =
            *(const bfrag*)(WTb + (nt * 16 + l15) * 64 + kt * 32 + q * 8);
    }
#pragma unroll
    for (int mt = 0; mt < 2; ++mt)
#pragma unroll
      for (int nt = 0; nt < 4; ++nt) {
        acc[mt][nt][0] = bbv[nt]; acc[mt][nt][1] = bbv[nt];
        acc[mt][nt][2] = bbv[nt]; acc[mt][nt][3] = bbv[nt];
      }
#pragma unroll
    for (int mt = 0; mt < 2; ++mt)
#pragma unroll
      for (int nt = 0; nt < 4; ++nt)
#pragma unroll
        for (int kt = 0; kt < 2; ++kt)
          acc[mt][nt] = __builtin_amdgcn_mfma_f32_16x16x32_bf16(
              af2[mt][kt], bwb[nt][kt], acc[mt][nt], 0, 0, 0);
#pragma unroll
    for (int nt = 0; nt < 4; ++nt)
#pragma unroll
      for (int mt = 0; mt < 2; ++mt)
#pragma unroll
        for (int i = 0; i < 4; ++i) {
          float z = tanh_fast(acc[mt][nt][i]);
          sAcc[nt] += z;
          qAcc[nt] = fmaf(z, z, qAcc[nt]);
        }
  }

#pragma unroll
  for (int nt = 0; nt < 4; ++nt) {
    float s = sAcc[nt], ss = qAcc[nt];
    s += __shfl_xor(s, 16); s += __shfl_xor(s, 32);
    ss += __shfl_xor(ss, 16); ss += __shfl_xor(ss, 32);
    if (q == 0) {
      P[(size_t)blockIdx.x * 128 + nt * 16 + l15] = s;
      P[(size_t)blockIdx.x * 128 + 64 + nt * 16 + l15] = ss;
    }
  }
}

// K_last: recompute Z5, Y5 = BN(Z5)+Y4, out = Y5 @ Wout + bout.
// Wave-autonomous, barrier-free (per-wave Wout copy).
__global__ __launch_bounds__(64) void k_last(
    const short* __restrict__ Y, const short* __restrict__ WTa,
    const float* __restrict__ ba, const float* __restrict__ ga,
    const float* __restrict__ bea, const float* __restrict__ sa,
    const float* __restrict__ Wout, const float* __restrict__ bout,
    float* __restrict__ out) {
  __shared__ __align__(16) short ly[32 * 72];
  __shared__ float lds_wo[192];

  const int lane = threadIdx.x & 63;
  const int l15 = lane & 15;
  const int q = lane >> 4;
  const size_t r0 = (size_t)blockIdx.x * 64;

  bfrag afn[2][2];
#pragma unroll
  for (int mt = 0; mt < 2; ++mt)
#pragma unroll
    for (int kt = 0; kt < 2; ++kt)
      afn[mt][kt] =
          *(const bfrag*)(Y + (r0 + mt * 16 + l15) * 64 + kt * 32 + q * 8);

  for (int i = lane; i < 192; i += 64) lds_wo[i] = Wout[i];
  float Av[4], Bv[4], bav[4];
#pragma unroll
  for (int nt = 0; nt < 4; ++nt) {
    int c = nt * 16 + l15;
    float mean = sa[c] * INV_B;
    float var = fmaf(-mean, mean, sa[64 + c] * INV_B);
    float A = ga[c] * rsqrtf(var + EPS);
    Av[nt] = A;
    Bv[nt] = fmaf(-A, mean, bea[c]);
    bav[nt] = ba[c];
  }
  bfrag bwa[4][2];
#pragma unroll
  for (int nt = 0; nt < 4; ++nt)
#pragma unroll
    for (int kt = 0; kt < 2; ++kt)
      bwa[nt][kt] =
          *(const bfrag*)(WTa + (nt * 16 + l15) * 64 + kt * 32 + q * 8);
  float bo0 = bout[0], bo1 = bout[1], bo2 = bout[2];

#pragma unroll
  for (int t = 0; t < 2; ++t) {
    const size_t rt = r0 + t * 32;
    bfrag af[2][2];
#pragma unroll
    for (int mt = 0; mt < 2; ++mt)
#pragma unroll
      for (int kt = 0; kt < 2; ++kt) {
        af[mt][kt] = afn[mt][kt];
        *(bfrag*)&ly[(mt * 16 + l15) * 72 + kt * 32 + q * 8] = af[mt][kt];
      }
    if (t == 0) {
#pragma unroll
      for (int mt = 0; mt < 2; ++mt)
#pragma unroll
        for (int kt = 0; kt < 2; ++kt)
          afn[mt][kt] = *(const bfrag*)(Y + (r0 + 32 + mt * 16 + l15) * 64 +
                                        kt * 32 + q * 8);
    }

    facc acc[2][4];
#pragma unroll
    for (int mt = 0; mt < 2; ++mt)
#pragma unroll
      for (int nt = 0; nt < 4; ++nt) {
        acc[mt][nt][0] = bav[nt]; acc[mt][nt][1] = bav[nt];
        acc[mt][nt][2] = bav[nt]; acc[mt][nt][3] = bav[nt];
      }
#pragma unroll
    for (int mt = 0; mt < 2; ++mt)
#pragma unroll
      for (int nt = 0; nt < 4; ++nt)
#pragma unroll
        for (int kt = 0; kt < 2; ++kt)
          acc[mt][nt] = __builtin_amdgcn_mfma_f32_16x16x32_bf16(
              af[mt][kt], bwa[nt][kt], acc[mt][nt], 0, 0, 0);
#pragma unroll
    for (int mt = 0; mt < 2; ++mt)
#pragma unroll
      for (int nt = 0; nt < 4; ++nt) {
        int c = nt * 16 + l15;
        float A = Av[nt], Bc = Bv[nt];
#pragma unroll
        for (int i = 0; i < 4; ++i) {
          int rl = mt * 16 + q * 4 + i;
          float z = tanh_fast(acc[mt][nt][i]);
          float yo = bf2f(ly[rl * 72 + c]);
          ly[rl * 72 + c] = f2bf(fmaf(A, z, Bc) + yo);
        }
      }

    // epilogue (wave-private): lane pair (2r,2r+1) handles local row r
    {
      int row = lane >> 1;
      int cb = (lane & 1) * 32;
      float o0 = 0.f, o1 = 0.f, o2 = 0.f;
#pragma unroll
      for (int jc = 0; jc < 4; ++jc) {
        bfrag v = *(const bfrag*)&ly[row * 72 + cb + jc * 8];
#pragma unroll
        for (int j = 0; j < 8; ++j) {
          float f = bf2f(v[j]);
          int jj = cb + jc * 8 + j;
          o0 = fmaf(f, lds_wo[jj * 3 + 0], o0);
          o1 = fmaf(f, lds_wo[jj * 3 + 1], o1);
          o2 = fmaf(f, lds_wo[jj * 3 + 2], o2);
        }
      }
      o0 += __shfl_xor(o0, 1);
      o1 += __shfl_xor(o1, 1);
      o2 += __shfl_xor(o2, 1);
      if ((lane & 1) == 0) {
        size_t ro = (rt + row) * 3;
        out[ro] = o0 + bo0;
        out[ro + 1] = o1 + bo1;
        out[ro + 2] = o2 + bo2;
      }
    }
  }
}

extern "C" void kernel_launch(void* const* d_in, const int* in_sizes, int n_in,
                              void* d_out, int out_size, void* d_ws,
                              size_t ws_size, hipStream_t stream) {
  (void)in_sizes; (void)n_in; (void)out_size; (void)ws_size;
  const float* x = (const float*)d_in[0];
  const float* bn0g = (const float*)d_in[1];
  const float* bn0b = (const float*)d_in[2];
  const float* W0 = (const float*)d_in[3];
  const float* b0 = (const float*)d_in[4];
  const float* gamma0 = (const float*)d_in[5];
  const float* beta0 = (const float*)d_in[6];
  const float* Wh = (const float*)d_in[7];
  const float* bh = (const float*)d_in[8];
  const float* gh = (const float*)d_in[9];
  const float* beh = (const float*)d_in[10];
  const float* Wout = (const float*)d_in[11];
  const float* bout = (const float*)d_in[12];
  float* out = (float*)d_out;

  char* ws = (char*)d_ws;
  short* Y = (short*)ws;                       // 1M x 64 bf16 = 128 MB
  const size_t YB = (size_t)NROWS * 64 * 2;
  float* stats = (float*)(ws + YB);            // [Sx 8][S1..S5 128 each]
  float* Sx = stats;
  float* S1 = stats + 8;
  float* S2 = stats + 136;
  float* S3 = stats + 264;
  float* S4 = stats + 392;
  float* S5 = stats + 520;
  short* WT = (short*)(ws + YB + 4096);        // 4 x 64 x 64 bf16 = 32 KB
  float* P = (float*)(ws + YB + 4096 + 32768); // partials: 16384x128 f32 = 8 MB

  hipMemsetAsync(stats, 0, 648 * sizeof(float), stream);
  k_prep<<<64, 256, 0, stream>>>(Wh, WT);
  k_stats_x<<<1024, 256, 0, stream>>>(x, P);
  k_reduce<8><<<8, 256, 0, stream>>>(P, Sx, 128);
  k_stats_z1<<<1024, 256, 0, stream>>>(x, bn0g, bn0b, W0, b0, Sx, P);
  k_reduce<128><<<8, 256, 0, stream>>>(P, S1, 128);
  k_first<<<BIGGRID, 64, 0, stream>>>(x, bn0g, bn0b, W0, b0, gamma0, beta0,
                                      Sx, S1, WT, bh, P, Y);
  k_reduce<128><<<128, 256, 0, stream>>>(P, S2, 128);
  k_mid<<<BIGGRID, 64, 0, stream>>>(Y, WT, bh, gh, beh, S2, WT + 4096,
                                    bh + 64, P);
  k_reduce<128><<<128, 256, 0, stream>>>(P, S3, 128);
  k_mid<<<BIGGRID, 64, 0, stream>>>(Y, WT + 4096, bh + 64, gh + 64, beh + 64,
                                    S3, WT + 2 * 4096, bh + 128, P);
  k_reduce<128><<<128, 256, 0, stream>>>(P, S4, 128);
  k_mid<<<BIGGRID, 64, 0, stream>>>(Y, WT + 2 * 4096, bh + 128, gh + 128,
                                    beh + 128, S4, WT + 3 * 4096, bh + 192, P);
  k_reduce<128><<<128, 256, 0, stream>>>(P, S5, 128);
  k_last<<<BIGGRID, 64, 0, stream>>>(Y, WT + 3 * 4096, bh + 192, gh + 192,
                                     beh + 192, S5, Wout, bout, out);
}